// Round 1
// baseline (462.803 us; speedup 1.0000x reference)
//
#include <hip/hip_runtime.h>
#include <math.h>

// B=32, P=3, D=300, N=2048. Inputs x,y [B,P,D,N] f32; out [B,P*N,3] f32.
//
// R3 design: occupancy fix. R2 had grid = 3072 waves = 12 waves/CU (30%
// occupancy) and only 36 VGPRs -> ~24-48 KB in flight per CU against ~900cy
// HBM latency -> 5 B/cy/CU (half of achievable). Pure streaming workload, so
// the lever is more resident waves: split D 3 more ways at grid level.
//
// Block = 192 threads = 3 waves, all on the same 64-n span. Each wave owns a
// 100-row D-chunk, split in-wave into 4 segments of 25 rows (lane = s*16+q,
// q = n-quad, s = segment). Grid = 3072 blocks = 9216 waves -> 10 blocks/CU
// resident = 30 waves/CU (2.5x R2). Cross-wave combine via 2.5 KB LDS.

constexpr int kB = 32;
constexpr int kP = 3;
constexpr int kD = 300;
constexpr int kN = 2048;
constexpr int kWaves = 3;                      // waves per block (grid-level D split)
constexpr int kSeg = 4;                        // in-wave D segments
constexpr int kRows = kD / (kWaves * kSeg);    // 25 d-rows per segment

__device__ inline void reduce4(float4& v) {
    v.x += __shfl_down(v.x, 32); v.y += __shfl_down(v.y, 32);
    v.z += __shfl_down(v.z, 32); v.w += __shfl_down(v.w, 32);
    v.x += __shfl_down(v.x, 16); v.y += __shfl_down(v.y, 16);
    v.z += __shfl_down(v.z, 16); v.w += __shfl_down(v.w, 16);
}

__global__ __launch_bounds__(192) void sim_measure_kernel(
    const float* __restrict__ x,
    const float* __restrict__ y,
    float* __restrict__ out)
{
    const int lane = threadIdx.x & 63;
    const int ww   = threadIdx.x >> 6;    // wave within block [0,3)
    const int q = lane & 15;              // n-quad index within 64-n span
    const int s = lane >> 4;              // in-wave D segment [0,4)

    const int bp = blockIdx.x >> 5;       // 32 blocks per (b,p)
    const int n0 = (blockIdx.x & 31) << 6;

    const int seg = ww * kSeg + s;        // global D segment [0,12), 25 rows each
    const size_t base = ((size_t)bp * kD + (size_t)seg * kRows) * kN
                      + (size_t)(n0 + q * 4);
    const float4* __restrict__ xp = (const float4*)(x + base);
    const float4* __restrict__ yp = (const float4*)(y + base);
    constexpr int kStride4 = kN / 4;      // 512 float4s between d-rows

    float4 dot = {0.f, 0.f, 0.f, 0.f};
    float4 xx  = {0.f, 0.f, 0.f, 0.f};
    float4 yy  = {0.f, 0.f, 0.f, 0.f};
    float4 l2s = {0.f, 0.f, 0.f, 0.f};
    float4 l1  = {0.f, 0.f, 0.f, 0.f};

    #pragma unroll 5
    for (int d = 0; d < kRows; ++d) {
        const float4 xv = xp[(size_t)d * kStride4];
        const float4 yv = yp[(size_t)d * kStride4];

        dot.x = fmaf(xv.x, yv.x, dot.x); dot.y = fmaf(xv.y, yv.y, dot.y);
        dot.z = fmaf(xv.z, yv.z, dot.z); dot.w = fmaf(xv.w, yv.w, dot.w);
        xx.x  = fmaf(xv.x, xv.x, xx.x);  xx.y  = fmaf(xv.y, xv.y, xx.y);
        xx.z  = fmaf(xv.z, xv.z, xx.z);  xx.w  = fmaf(xv.w, xv.w, xx.w);
        yy.x  = fmaf(yv.x, yv.x, yy.x);  yy.y  = fmaf(yv.y, yv.y, yy.y);
        yy.z  = fmaf(yv.z, yv.z, yy.z);  yy.w  = fmaf(yv.w, yv.w, yy.w);
        const float dx = xv.x - yv.x, dy = xv.y - yv.y,
                    dz = xv.z - yv.z, dw = xv.w - yv.w;
        l2s.x = fmaf(dx, dx, l2s.x); l2s.y = fmaf(dy, dy, l2s.y);
        l2s.z = fmaf(dz, dz, l2s.z); l2s.w = fmaf(dw, dw, l2s.w);
        l1.x += fabsf(dx); l1.y += fabsf(dy);
        l1.z += fabsf(dz); l1.w += fabsf(dw);
    }

    // In-wave: combine the 4 D segments (lanes q, q+16, q+32, q+48) -> lanes 0..15
    reduce4(dot); reduce4(xx); reduce4(yy); reduce4(l2s); reduce4(l1);

    // Cross-wave: waves 1,2 publish partials; wave 0 combines + finalizes.
    __shared__ float4 lds[kWaves - 1][16][5];
    if (ww > 0 && s == 0) {
        lds[ww - 1][q][0] = dot;
        lds[ww - 1][q][1] = xx;
        lds[ww - 1][q][2] = yy;
        lds[ww - 1][q][3] = l2s;
        lds[ww - 1][q][4] = l1;
    }
    __syncthreads();

    if (ww == 0 && s == 0) {
        #pragma unroll
        for (int w = 0; w < kWaves - 1; ++w) {
            const float4 a = lds[w][q][0];
            const float4 b = lds[w][q][1];
            const float4 c = lds[w][q][2];
            const float4 e = lds[w][q][3];
            const float4 f = lds[w][q][4];
            dot.x += a.x; dot.y += a.y; dot.z += a.z; dot.w += a.w;
            xx.x  += b.x; xx.y  += b.y; xx.z  += b.z; xx.w  += b.w;
            yy.x  += c.x; yy.y  += c.y; yy.z  += c.z; yy.w  += c.w;
            l2s.x += e.x; l2s.y += e.y; l2s.z += e.z; l2s.w += e.w;
            l1.x  += f.x; l1.y  += f.y; l1.z  += f.z; l1.w  += f.w;
        }

        float4 o0, o1, o2;  // 12 floats: {cos,l2,l1} x 4 n
        const float c0 = dot.x / (sqrtf(xx.x) * sqrtf(yy.x));
        const float c1 = dot.y / (sqrtf(xx.y) * sqrtf(yy.y));
        const float c2 = dot.z / (sqrtf(xx.z) * sqrtf(yy.z));
        const float c3 = dot.w / (sqrtf(xx.w) * sqrtf(yy.w));
        const float e0 = sqrtf(l2s.x), e1 = sqrtf(l2s.y),
                    e2 = sqrtf(l2s.z), e3 = sqrtf(l2s.w);

        o0.x = c0;   o0.y = e0;   o0.z = l1.x; o0.w = c1;
        o1.x = e1;   o1.y = l1.y; o1.z = c2;   o1.w = e2;
        o2.x = l1.z; o2.y = c3;   o2.z = e3;   o2.w = l1.w;

        // out offset: (bp*N + n0 + q*4)*3 floats -> multiple of 12 -> 16B aligned
        float4* op = (float4*)(out + ((size_t)bp * kN + (size_t)(n0 + q * 4)) * 3);
        op[0] = o0; op[1] = o1; op[2] = o2;
    }
}

extern "C" void kernel_launch(void* const* d_in, const int* in_sizes, int n_in,
                              void* d_out, int out_size, void* d_ws, size_t ws_size,
                              hipStream_t stream)
{
    const float* x = (const float*)d_in[0];
    const float* y = (const float*)d_in[1];
    float* out = (float*)d_out;

    const int grid  = kB * kP * (kN / 64);   // 3072 blocks
    const int block = 64 * kWaves;           // 192 threads = 3 waves

    sim_measure_kernel<<<grid, block, 0, stream>>>(x, y, out);
}

// Round 2
// 453.410 us; speedup vs baseline: 1.0207x; 1.0207x over previous
//
#include <hip/hip_runtime.h>
#include <math.h>

// B=32, P=3, D=300, N=2048. Inputs x,y [B,P,D,N] f32; out [B,P*N,3] f32.
//
// R4 design: force memory-level parallelism. R2/R3 post-mortem: perf flat at
// ~150-163us regardless of occupancy (30% vs 68%) because the compiler
// minimized VGPRs (36/24) and kept only ~1-2 load pairs in flight per wave ->
// ~30-48 KB in flight per CU vs the ~100+ KB Little's law wants at ~6 TB/s.
//
// Fix: group loads 5 rows at a time into fully-unrolled float4 arrays (all
// indices compile-time -> registers, not scratch). The 10 loads of a group
// have no consumer between them, forcing ~40 live load-dest VGPRs and 10 KB
// in flight per wave. Mapping unchanged from R3: block = 3 waves on one 64-n
// span; D split 12 ways (3 waves x 4 in-wave segments x 25 rows).

constexpr int kB = 32;
constexpr int kP = 3;
constexpr int kD = 300;
constexpr int kN = 2048;
constexpr int kWaves = 3;                      // waves per block (grid-level D split)
constexpr int kSeg = 4;                        // in-wave D segments
constexpr int kRows = kD / (kWaves * kSeg);    // 25 d-rows per segment
constexpr int kG = 5;                          // load-batch depth (rows)
constexpr int kNG = kRows / kG;                // 5 groups

__device__ inline void reduce4(float4& v) {
    v.x += __shfl_down(v.x, 32); v.y += __shfl_down(v.y, 32);
    v.z += __shfl_down(v.z, 32); v.w += __shfl_down(v.w, 32);
    v.x += __shfl_down(v.x, 16); v.y += __shfl_down(v.y, 16);
    v.z += __shfl_down(v.z, 16); v.w += __shfl_down(v.w, 16);
}

__global__ __launch_bounds__(192) void sim_measure_kernel(
    const float* __restrict__ x,
    const float* __restrict__ y,
    float* __restrict__ out)
{
    const int lane = threadIdx.x & 63;
    const int ww   = threadIdx.x >> 6;    // wave within block [0,3)
    const int q = lane & 15;              // n-quad index within 64-n span
    const int s = lane >> 4;              // in-wave D segment [0,4)

    const int bp = blockIdx.x >> 5;       // 32 blocks per (b,p)
    const int n0 = (blockIdx.x & 31) << 6;

    const int seg = ww * kSeg + s;        // global D segment [0,12), 25 rows each
    const size_t base = ((size_t)bp * kD + (size_t)seg * kRows) * kN
                      + (size_t)(n0 + q * 4);
    const float4* __restrict__ xp = (const float4*)(x + base);
    const float4* __restrict__ yp = (const float4*)(y + base);
    constexpr int kStride4 = kN / 4;      // 512 float4s between d-rows

    float4 dot = {0.f, 0.f, 0.f, 0.f};
    float4 xx  = {0.f, 0.f, 0.f, 0.f};
    float4 yy  = {0.f, 0.f, 0.f, 0.f};
    float4 l2s = {0.f, 0.f, 0.f, 0.f};
    float4 l1  = {0.f, 0.f, 0.f, 0.f};

    #pragma unroll
    for (int g = 0; g < kNG; ++g) {
        // Phase 1: issue all 10 loads of this group back-to-back.
        // Fully unrolled -> static indices -> registers (rule #20).
        float4 xs[kG], ys[kG];
        #pragma unroll
        for (int j = 0; j < kG; ++j) {
            xs[j] = xp[(size_t)(g * kG + j) * kStride4];
            ys[j] = yp[(size_t)(g * kG + j) * kStride4];
        }
        // Phase 2: consume. (Scheduler may overlap with group g+1's loads.)
        #pragma unroll
        for (int j = 0; j < kG; ++j) {
            const float4 xv = xs[j];
            const float4 yv = ys[j];
            dot.x = fmaf(xv.x, yv.x, dot.x); dot.y = fmaf(xv.y, yv.y, dot.y);
            dot.z = fmaf(xv.z, yv.z, dot.z); dot.w = fmaf(xv.w, yv.w, dot.w);
            xx.x  = fmaf(xv.x, xv.x, xx.x);  xx.y  = fmaf(xv.y, xv.y, xx.y);
            xx.z  = fmaf(xv.z, xv.z, xx.z);  xx.w  = fmaf(xv.w, xv.w, xx.w);
            yy.x  = fmaf(yv.x, yv.x, yy.x);  yy.y  = fmaf(yv.y, yv.y, yy.y);
            yy.z  = fmaf(yv.z, yv.z, yy.z);  yy.w  = fmaf(yv.w, yv.w, yy.w);
            const float dx = xv.x - yv.x, dy = xv.y - yv.y,
                        dz = xv.z - yv.z, dw = xv.w - yv.w;
            l2s.x = fmaf(dx, dx, l2s.x); l2s.y = fmaf(dy, dy, l2s.y);
            l2s.z = fmaf(dz, dz, l2s.z); l2s.w = fmaf(dw, dw, l2s.w);
            l1.x += fabsf(dx); l1.y += fabsf(dy);
            l1.z += fabsf(dz); l1.w += fabsf(dw);
        }
    }

    // In-wave: combine the 4 D segments (lanes q, q+16, q+32, q+48) -> lanes 0..15
    reduce4(dot); reduce4(xx); reduce4(yy); reduce4(l2s); reduce4(l1);

    // Cross-wave: waves 1,2 publish partials; wave 0 combines + finalizes.
    __shared__ float4 lds[kWaves - 1][16][5];
    if (ww > 0 && s == 0) {
        lds[ww - 1][q][0] = dot;
        lds[ww - 1][q][1] = xx;
        lds[ww - 1][q][2] = yy;
        lds[ww - 1][q][3] = l2s;
        lds[ww - 1][q][4] = l1;
    }
    __syncthreads();

    if (ww == 0 && s == 0) {
        #pragma unroll
        for (int w = 0; w < kWaves - 1; ++w) {
            const float4 a = lds[w][q][0];
            const float4 b = lds[w][q][1];
            const float4 c = lds[w][q][2];
            const float4 e = lds[w][q][3];
            const float4 f = lds[w][q][4];
            dot.x += a.x; dot.y += a.y; dot.z += a.z; dot.w += a.w;
            xx.x  += b.x; xx.y  += b.y; xx.z  += b.z; xx.w  += b.w;
            yy.x  += c.x; yy.y  += c.y; yy.z  += c.z; yy.w  += c.w;
            l2s.x += e.x; l2s.y += e.y; l2s.z += e.z; l2s.w += e.w;
            l1.x  += f.x; l1.y  += f.y; l1.z  += f.z; l1.w  += f.w;
        }

        float4 o0, o1, o2;  // 12 floats: {cos,l2,l1} x 4 n
        const float c0 = dot.x / (sqrtf(xx.x) * sqrtf(yy.x));
        const float c1 = dot.y / (sqrtf(xx.y) * sqrtf(yy.y));
        const float c2 = dot.z / (sqrtf(xx.z) * sqrtf(yy.z));
        const float c3 = dot.w / (sqrtf(xx.w) * sqrtf(yy.w));
        const float e0 = sqrtf(l2s.x), e1 = sqrtf(l2s.y),
                    e2 = sqrtf(l2s.z), e3 = sqrtf(l2s.w);

        o0.x = c0;   o0.y = e0;   o0.z = l1.x; o0.w = c1;
        o1.x = e1;   o1.y = l1.y; o1.z = c2;   o1.w = e2;
        o2.x = l1.z; o2.y = c3;   o2.z = e3;   o2.w = l1.w;

        // out offset: (bp*N + n0 + q*4)*3 floats -> multiple of 12 -> 16B aligned
        float4* op = (float4*)(out + ((size_t)bp * kN + (size_t)(n0 + q * 4)) * 3);
        op[0] = o0; op[1] = o1; op[2] = o2;
    }
}

extern "C" void kernel_launch(void* const* d_in, const int* in_sizes, int n_in,
                              void* d_out, int out_size, void* d_ws, size_t ws_size,
                              hipStream_t stream)
{
    const float* x = (const float*)d_in[0];
    const float* y = (const float*)d_in[1];
    float* out = (float*)d_out;

    const int grid  = kB * kP * (kN / 64);   // 3072 blocks
    const int block = 64 * kWaves;           // 192 threads = 3 waves

    sim_measure_kernel<<<grid, block, 0, stream>>>(x, y, out);
}